// Round 2
// baseline (442.418 us; speedup 1.0000x reference)
//
#include <hip/hip_runtime.h>
#include <hip/hip_bf16.h>

// Problem constants (fixed by reference setup_inputs)
constexpr int BS = 64, C = 256, NH = 4, DH = 64, T = 6, D = 192;
constexpr int HW = 3136;
constexpr int NT = 112;                  // chunk size over HW (7 n-tiles of 16)
constexpr int S = 4, CPB = 7;            // HW splits per (b,h), chunks per split (S*CPB*NT = 3136)
constexpr int PNF = 136;                 // fch/pw row stride (272B: 16B-aligned b128 frags)
constexpr int PNS = 116;                 // st row stride (fp32)
constexpr int QP = 72;                   // qs row stride (144B, 16B-aligned)
constexpr float SCALE = 0.125f;          // dh^-0.5
constexpr float LN_EPS = 1e-5f;

typedef short bf16x8 __attribute__((ext_vector_type(8)));
typedef float f32x4 __attribute__((ext_vector_type(4)));

__device__ inline unsigned short f2bf(float x) {
    union { float f; unsigned u; } v; v.f = x;
    unsigned r = v.u + 0x7FFFu + ((v.u >> 16) & 1u);   // RNE
    return (unsigned short)(r >> 16);
}

// pack 4 floats -> 4 bf16 and store 8B to LDS
__device__ inline void st_bf8(unsigned short* dst, float4 p) {
    unsigned lo = (unsigned)f2bf(p.x) | ((unsigned)f2bf(p.y) << 16);
    unsigned hi = (unsigned)f2bf(p.z) | ((unsigned)f2bf(p.w) << 16);
    *(uint2*)dst = make_uint2(lo, hi);
}

// Workgroup barrier that drains ONLY lgkm (LDS) — keeps global prefetch
// loads in flight across the barrier (unlike __syncthreads, which drains
// vmcnt(0) and would kill the 2-deep pipeline).
__device__ inline void wg_barrier_lgkm() {
    asm volatile("s_waitcnt lgkmcnt(0)" ::: "memory");
    __builtin_amdgcn_s_barrier();
    asm volatile("" ::: "memory");
}

// ---------------------------------------------------------------------------
// Kernel 1: q = tokens @ q_w^T + q_b ; gate = h_sigmoid(tokens @ alpha_w^T + alpha_b)*2
// 64 blocks: weight rows amortized over all 6 tokens (do NOT fuse into the
// split attention grid — round-1 showed that de-amortizes q_w into ~1GB of L2
// traffic and regressed 45us).
// ---------------------------------------------------------------------------
__global__ __launch_bounds__(256) void qalpha_kernel(
    const float* __restrict__ tokens,   // [T,BS,D]
    const float* __restrict__ q_w,      // [C,D]
    const float* __restrict__ q_b,      // [C]
    const float* __restrict__ alpha_w,  // [C,D]
    const float* __restrict__ alpha_b,  // [C]
    float* __restrict__ q_ws,           // [T,BS,C]
    float* __restrict__ alp_ws)         // [T,BS,C]
{
    int b = blockIdx.x;
    int c = threadIdx.x;
    __shared__ float tok_s[T][D];
    for (int i = c; i < T * (D / 4); i += 256) {
        int t = i / (D / 4), v = i % (D / 4);
        *(float4*)&tok_s[t][4 * v] =
            *(const float4*)&tokens[((size_t)t * BS + b) * D + 4 * v];
    }
    __syncthreads();

    const float4* qr = (const float4*)(q_w + (size_t)c * D);
    const float4* ar = (const float4*)(alpha_w + (size_t)c * D);
    float accq[T] = {0, 0, 0, 0, 0, 0};
    float acca[T] = {0, 0, 0, 0, 0, 0};
    for (int v = 0; v < D / 4; ++v) {
        float4 qw4 = qr[v], aw4 = ar[v];
#pragma unroll
        for (int t = 0; t < T; ++t) {
            float4 t4 = *(const float4*)&tok_s[t][4 * v];
            accq[t] += qw4.x * t4.x + qw4.y * t4.y + qw4.z * t4.z + qw4.w * t4.w;
            acca[t] += aw4.x * t4.x + aw4.y * t4.y + aw4.z * t4.z + aw4.w * t4.w;
        }
    }
    float qb = q_b[c], ab = alpha_b[c];
#pragma unroll
    for (int t = 0; t < T; ++t) {
        size_t idx = ((size_t)t * BS + b) * C + c;
        q_ws[idx] = accq[t] + qb;
        float aa = acca[t] + ab + 3.0f;
        alp_ws[idx] = fminf(fmaxf(aa, 0.0f), 6.0f) * (2.0f / 6.0f);
    }
}

// ---------------------------------------------------------------------------
// Kernel 2: fused attention + mlp via MFMA, split over HW.
// grid = BS*NH*S = 1024 (exactly 4 blocks/CU resident); 384 threads = 6 waves.
//   scores: S[t,n] = Q x F     (A=Q b128 frags, B=F strided-u16 frags)
//   PV+MLP: D[c,t~] = F x [P;W] (A=F b128, B=PW b128; t~0-5=O, 6-11=MLP)
// Staging is 2-deep software-pipelined: chunks cc+1 and cc+2 are in flight in
// registers (two named PF sets, static indexing) while chunk cc computes; all
// in-loop barriers drain lgkm only, so global loads survive across them.
// ---------------------------------------------------------------------------
struct PF { float4 f0, f1, f2, f3, f4, m; };

__global__ __launch_bounds__(384, 6) void fused_attn_mlp(
    const float* __restrict__ feat,     // [BS,C,HW]
    const float* __restrict__ mlp_w,    // [T,HW]
    const float* __restrict__ q_ws,     // [T,BS,C]
    float* __restrict__ out_attn,       // [BS,NH,T,HW] (pre-softmax scores)
    float* __restrict__ o_part,         // [BS*NH*S][T][DH]
    float* __restrict__ mlp_part,       // [BS*NH*S][T][DH]
    float* __restrict__ ml_part)        // [BS*NH*S][T][2]
{
    int bh = blockIdx.x / S, sp = blockIdx.x % S;
    int b = bh / NH, h = bh % NH;
    int tid = threadIdx.x;
    int wave = tid >> 6, lane = tid & 63;
    int col = lane & 15, quad = lane >> 4;

    __shared__ unsigned short fch[DH][PNF];   // 17.4 KB bf16 features chunk
    __shared__ unsigned short pw[16][PNF];    // 4.4 KB  rows 0-5 = P, 6-11 = W, 12-15 = 0
    __shared__ unsigned short qs[16][QP];     // 2.3 KB  bf16 Q (rows 6-15 garbage; discarded)
    __shared__ float st[T][PNS];              // 2.8 KB  fp32 scores chunk
    __shared__ float m_s[T], l_s[T], al_s[T];

    const float* fbase = feat + ((size_t)b * C + h * DH) * HW;
    float* obase = out_attn + ((size_t)bh * T) * HW;

    // per-thread staging offsets (rows of 28 float4 = 112 cols)
    const int o0 = (tid / 28) * HW + 4 * (tid % 28);           // also mlp_w offset
    const int o1 = ((tid + 384) / 28) * HW + 4 * ((tid + 384) % 28);
    const int o2 = ((tid + 768) / 28) * HW + 4 * ((tid + 768) % 28);
    const int o3 = ((tid + 1152) / 28) * HW + 4 * ((tid + 1152) % 28);
    const int o4 = ((tid + 1536) / 28) * HW + 4 * ((tid + 1536) % 28);

    auto pf_issue = [&](PF& p, int n0) {
        p.f0 = *(const float4*)&fbase[o0 + n0];
        p.f1 = *(const float4*)&fbase[o1 + n0];
        p.f2 = *(const float4*)&fbase[o2 + n0];
        p.f3 = *(const float4*)&fbase[o3 + n0];
        if (tid < 256) p.f4 = *(const float4*)&fbase[o4 + n0];
        if (tid < 168) p.m  = *(const float4*)&mlp_w[o0 + n0];
    };
    auto pf_commit = [&](const PF& p) {
        st_bf8(&fch[tid / 28][4 * (tid % 28)], p.f0);
        st_bf8(&fch[(tid + 384) / 28][4 * ((tid + 384) % 28)], p.f1);
        st_bf8(&fch[(tid + 768) / 28][4 * ((tid + 768) % 28)], p.f2);
        st_bf8(&fch[(tid + 1152) / 28][4 * ((tid + 1152) % 28)], p.f3);
        if (tid < 256) st_bf8(&fch[(tid + 1536) / 28][4 * ((tid + 1536) % 28)], p.f4);
        if (tid < 168) st_bf8(&pw[6 + tid / 28][4 * (tid % 28)], p.m);
    };

    // ---- issue chunks 0 and 1 (2-deep) before any LDS work
    const int nsp = sp * CPB * NT;
    PF A, B;
    pf_issue(A, nsp);
    pf_issue(B, nsp + NT);

    // ---- one-time zero of pads (staging never touches these)
    for (int i = tid; i < 16 * PNF; i += 384) pw[i / PNF][i % PNF] = 0;
    for (int i = tid; i < DH * 16; i += 384) fch[i / 16][112 + (i % 16)] = 0;
    if (tid < T) { m_s[tid] = -3e38f; l_s[tid] = 0.f; }
    // ---- stage Q bf16 (rows 0-5); one load per thread (t=wave, c2=lane)
    qs[wave][lane] = f2bf(q_ws[((size_t)wave * BS + b) * C + h * DH + lane]);

    f32x4 accPW = {0.f, 0.f, 0.f, 0.f};    // waves 0-3: [c-tile=wave][t~=col]
    wg_barrier_lgkm();

    auto chunk_body = [&](int cc, PF& P) {
        const int n0 = nsp + cc * NT;

        // ---- commit prefetched chunk cc to LDS as bf16 (vmcnt wait by dep)
        pf_commit(P);
        // ---- refill this set with chunk cc+2; stays in flight 2 chunk-periods
        if (cc + 2 < CPB) pf_issue(P, n0 + 2 * NT);
        wg_barrier_lgkm();

        // ---- scores MFMA: n-tile(s) per wave
        for (int tile = wave; tile < 7; tile += 6) {
            bf16x8 a0 = *(const bf16x8*)&qs[col][quad * 8];
            bf16x8 a1 = *(const bf16x8*)&qs[col][32 + quad * 8];
            bf16x8 b0, b1;
#pragma unroll
            for (int j = 0; j < 8; ++j) {
                b0[j] = (short)fch[quad * 8 + j][tile * 16 + col];
                b1[j] = (short)fch[32 + quad * 8 + j][tile * 16 + col];
            }
            f32x4 acc = {0.f, 0.f, 0.f, 0.f};
            acc = __builtin_amdgcn_mfma_f32_16x16x32_bf16(a0, b0, acc, 0, 0, 0);
            acc = __builtin_amdgcn_mfma_f32_16x16x32_bf16(a1, b1, acc, 0, 0, 0);
#pragma unroll
            for (int reg = 0; reg < 4; ++reg) {
                int r = quad * 4 + reg;
                if (r < 6) st[r][tile * 16 + col] = acc[reg] * SCALE;
            }
        }
        wg_barrier_lgkm();

        // ---- online softmax (wave t) + coalesced score write-out
        {
            int t = wave;
            float v0 = st[t][lane];
            float v1 = (lane + 64 < NT) ? st[t][lane + 64] : -3e38f;
            float mloc = fmaxf(v0, v1);
#pragma unroll
            for (int off = 32; off; off >>= 1) mloc = fmaxf(mloc, __shfl_down(mloc, off));
            mloc = __shfl(mloc, 0);
            float m_old = m_s[t], m_new = fmaxf(m_old, mloc);
            float p0 = __expf(v0 - m_new);
            float p1 = (lane + 64 < NT) ? __expf(v1 - m_new) : 0.f;
            pw[t][lane] = f2bf(p0);
            if (lane + 64 < NT) pw[t][lane + 64] = f2bf(p1);
            float ssum = p0 + p1;
#pragma unroll
            for (int off = 32; off; off >>= 1) ssum += __shfl_down(ssum, off);
            if (lane == 0) {
                float alpha = __expf(m_old - m_new);
                l_s[t] = l_s[t] * alpha + ssum;
                m_s[t] = m_new;
                al_s[t] = alpha;
            }
            if (lane < NT / 4) {   // coalesced float4 out_attn write
                *(float4*)&obase[(size_t)t * HW + n0 + 4 * lane] =
                    *(const float4*)&st[t][4 * lane];
            }
        }
        wg_barrier_lgkm();

        // ---- PV + MLP MFMA: wave = c-tile (waves 0-3)
        if (wave < 4) {
            float alpha = (col < 6) ? al_s[col] : 1.0f;
            accPW *= alpha;
#pragma unroll
            for (int ks = 0; ks < 4; ++ks) {
                bf16x8 af = *(const bf16x8*)&fch[wave * 16 + col][ks * 32 + quad * 8];
                bf16x8 bf = *(const bf16x8*)&pw[col][ks * 32 + quad * 8];
                accPW = __builtin_amdgcn_mfma_f32_16x16x32_bf16(af, bf, accPW, 0, 0, 0);
            }
        }
        wg_barrier_lgkm();   // fch/pw/st reused next chunk
    };

    // CPB=7: A holds even chunks {0,2,4,6}, B holds odd {1,3,5}. Static set
    // selection (rule: no runtime-indexed register arrays).
#pragma unroll 1
    for (int cc = 0; cc < CPB; cc += 2) {
        chunk_body(cc, A);
        if (cc + 1 < CPB) chunk_body(cc + 1, B);
    }

    // ---- epilogue: scatter D tiles to partials
    if (wave < 4) {
#pragma unroll
        for (int reg = 0; reg < 4; ++reg) {
            int c2 = wave * 16 + quad * 4 + reg;   // row = channel
            if (col < 6) {
                o_part[((size_t)blockIdx.x * T + col) * DH + c2] = accPW[reg];
            } else if (col < 12) {
                mlp_part[((size_t)blockIdx.x * T + (col - 6)) * DH + c2] = accPW[reg];
            }
        }
    }
    if (tid < 2 * T) {
        int t = tid >> 1;
        ml_part[((size_t)blockIdx.x * T + t) * 2 + (tid & 1)] =
            (tid & 1) ? l_s[t] : m_s[t];
    }
}

// ---------------------------------------------------------------------------
// Kernel 3: merge split partials + gate + proj + residual + LayerNorm.
// ---------------------------------------------------------------------------
__global__ __launch_bounds__(256) void merge_proj_ln_kernel(
    const float* __restrict__ o_part,
    const float* __restrict__ mlp_part,
    const float* __restrict__ ml_part,
    const float* __restrict__ mlp_b,    // [T]
    const float* __restrict__ alp_ws,   // [T,BS,C]
    const float* __restrict__ tokens,   // [T,BS,D]
    const float* __restrict__ proj_w,   // [D,C]
    const float* __restrict__ proj_b,   // [D]
    const float* __restrict__ ln_g,     // [D]
    const float* __restrict__ ln_b,     // [D]
    float* __restrict__ out_tok)        // [T,BS,D]
{
    int tb = blockIdx.x;
    int t = tb / BS, b = tb % BS;
    int tid = threadIdx.x;
    __shared__ float g_s[C];
    __shared__ float r1[4], r2[4];

    {
        int c = tid;
        int h = c >> 6, cl = c & 63;
        int bh = b * NH + h;
        float m[S], l[S];
        float M = -3e38f;
#pragma unroll
        for (int s = 0; s < S; ++s) {
            size_t blk = (size_t)(bh * S + s);
            m[s] = ml_part[(blk * T + t) * 2 + 0];
            l[s] = ml_part[(blk * T + t) * 2 + 1];
            M = fmaxf(M, m[s]);
        }
        float L = 0.f, O = 0.f, MLP = 0.f;
#pragma unroll
        for (int s = 0; s < S; ++s) {
            float w = __expf(m[s] - M);
            size_t blk = (size_t)(bh * S + s);
            size_t pidx = (blk * T + t) * DH + cl;
            L += l[s] * w;
            O += o_part[pidx] * w;
            MLP += mlp_part[pidx];
        }
        size_t idx = (size_t)tb * C + c;
        g_s[c] = (MLP + mlp_b[t] + O / L) * alp_ws[idx];
    }
    __syncthreads();

    if (tid < D) {
        int d = tid;
        float acc = proj_b[d] + tokens[(size_t)tb * D + d];
        const float4* pr = (const float4*)(proj_w + (size_t)d * C);
#pragma unroll 8
        for (int v = 0; v < C / 4; ++v) {
            float4 w4 = pr[v];
            float4 g4 = *(const float4*)&g_s[4 * v];
            acc += w4.x * g4.x + w4.y * g4.y + w4.z * g4.z + w4.w * g4.w;
        }

        float s1 = acc, s2 = acc * acc;
#pragma unroll
        for (int off = 32; off; off >>= 1) { s1 += __shfl_down(s1, off); s2 += __shfl_down(s2, off); }
        int wv = d >> 6, lane = d & 63;
        if (lane == 0) { r1[wv] = s1; r2[wv] = s2; }
        __syncthreads();
        float sum1 = r1[0] + r1[1] + r1[2];
        float sum2 = r2[0] + r2[1] + r2[2];
        float mu = sum1 * (1.0f / D);
        float var = sum2 * (1.0f / D) - mu * mu;
        float inv = rsqrtf(var + LN_EPS);
        out_tok[(size_t)tb * D + d] = (acc - mu) * inv * ln_g[d] + ln_b[d];
    } else {
        __syncthreads();
    }
}

// ---------------------------------------------------------------------------
extern "C" void kernel_launch(void* const* d_in, const int* in_sizes, int n_in,
                              void* d_out, int out_size, void* d_ws, size_t ws_size,
                              hipStream_t stream) {
    const float* features = (const float*)d_in[0];
    const float* tokens   = (const float*)d_in[1];
    const float* mlp_w    = (const float*)d_in[2];
    const float* mlp_b    = (const float*)d_in[3];
    const float* q_w      = (const float*)d_in[4];
    const float* q_b      = (const float*)d_in[5];
    const float* alpha_w  = (const float*)d_in[6];
    const float* alpha_b  = (const float*)d_in[7];
    const float* proj_w   = (const float*)d_in[8];
    const float* proj_b   = (const float*)d_in[9];
    const float* ln_g     = (const float*)d_in[10];
    const float* ln_b     = (const float*)d_in[11];

    float* out_tok  = (float*)d_out;                   // [T,BS,D]
    float* out_attn = (float*)d_out + T * BS * D;      // [BS,NH,T,HW]

    constexpr int NBLK = BS * NH * S;                  // 1024
    float* q_ws     = (float*)d_ws;                    // T*BS*C
    float* alp_ws   = q_ws + T * BS * C;               // T*BS*C
    float* ml_part  = alp_ws + T * BS * C;             // NBLK*T*2
    float* o_part   = ml_part + NBLK * T * 2;          // NBLK*T*DH
    float* mlp_part = o_part + NBLK * T * DH;          // NBLK*T*DH

    qalpha_kernel<<<BS, 256, 0, stream>>>(
        tokens, q_w, q_b, alpha_w, alpha_b, q_ws, alp_ws);

    fused_attn_mlp<<<NBLK, 384, 0, stream>>>(
        features, mlp_w, q_ws, out_attn, o_part, mlp_part, ml_part);

    merge_proj_ln_kernel<<<T * BS, 256, 0, stream>>>(
        o_part, mlp_part, ml_part, mlp_b, alp_ws, tokens,
        proj_w, proj_b, ln_g, ln_b, out_tok);
}

// Round 3
// 347.667 us; speedup vs baseline: 1.2725x; 1.2725x over previous
//
#include <hip/hip_runtime.h>
#include <hip/hip_bf16.h>

// Problem constants (fixed by reference setup_inputs)
constexpr int BS = 64, C = 256, NH = 4, DH = 64, T = 6, D = 192;
constexpr int HW = 3136;
constexpr int NT = 112;                  // chunk size over HW (7 n-tiles of 16)
constexpr int S = 7, CPB = 4;            // HW splits per (b,h), chunks per split
constexpr int PNF = 136;                 // fch/pw row stride (272B: 16B-aligned b128 frags)
constexpr int PNS = 116;                 // st row stride (fp32)
constexpr int QP = 72;                   // qs row stride (144B, 16B-aligned)
constexpr float SCALE = 0.125f;          // dh^-0.5
constexpr float LN_EPS = 1e-5f;

typedef short bf16x8 __attribute__((ext_vector_type(8)));
typedef float f32x4 __attribute__((ext_vector_type(4)));

__device__ inline unsigned short f2bf(float x) {
    union { float f; unsigned u; } v; v.f = x;
    unsigned r = v.u + 0x7FFFu + ((v.u >> 16) & 1u);   // RNE
    return (unsigned short)(r >> 16);
}

// pack 4 floats -> 4 bf16 and store 8B to LDS
__device__ inline void st_bf8(unsigned short* dst, float4 p) {
    unsigned lo = (unsigned)f2bf(p.x) | ((unsigned)f2bf(p.y) << 16);
    unsigned hi = (unsigned)f2bf(p.z) | ((unsigned)f2bf(p.w) << 16);
    *(uint2*)dst = make_uint2(lo, hi);
}

// Workgroup barrier that drains ONLY lgkm (LDS) — keeps global prefetch
// loads in flight across the barrier (unlike __syncthreads, which drains
// vmcnt(0) and would kill the pipeline).
__device__ inline void wg_barrier_lgkm() {
    asm volatile("s_waitcnt lgkmcnt(0)" ::: "memory");
    __builtin_amdgcn_s_barrier();
    asm volatile("" ::: "memory");
}

// ---------------------------------------------------------------------------
// Kernel 1: q = tokens @ q_w^T + q_b ; gate = h_sigmoid(tokens @ alpha_w^T + alpha_b)*2
// 64 blocks: weight rows amortized over all 6 tokens. (R1 showed fusing this
// into the split attention grid de-amortizes the weights and regresses ~50us.)
// ---------------------------------------------------------------------------
__global__ __launch_bounds__(256) void qalpha_kernel(
    const float* __restrict__ tokens,   // [T,BS,D]
    const float* __restrict__ q_w,      // [C,D]
    const float* __restrict__ q_b,      // [C]
    const float* __restrict__ alpha_w,  // [C,D]
    const float* __restrict__ alpha_b,  // [C]
    float* __restrict__ q_ws,           // [T,BS,C]
    float* __restrict__ alp_ws)         // [T,BS,C]
{
    int b = blockIdx.x;
    int c = threadIdx.x;
    __shared__ float tok_s[T][D];
    for (int i = c; i < T * (D / 4); i += 256) {
        int t = i / (D / 4), v = i % (D / 4);
        *(float4*)&tok_s[t][4 * v] =
            *(const float4*)&tokens[((size_t)t * BS + b) * D + 4 * v];
    }
    __syncthreads();

    const float4* qr = (const float4*)(q_w + (size_t)c * D);
    const float4* ar = (const float4*)(alpha_w + (size_t)c * D);
    float accq[T] = {0, 0, 0, 0, 0, 0};
    float acca[T] = {0, 0, 0, 0, 0, 0};
    for (int v = 0; v < D / 4; ++v) {
        float4 qw4 = qr[v], aw4 = ar[v];
#pragma unroll
        for (int t = 0; t < T; ++t) {
            float4 t4 = *(const float4*)&tok_s[t][4 * v];
            accq[t] += qw4.x * t4.x + qw4.y * t4.y + qw4.z * t4.z + qw4.w * t4.w;
            acca[t] += aw4.x * t4.x + aw4.y * t4.y + aw4.z * t4.z + aw4.w * t4.w;
        }
    }
    float qb = q_b[c], ab = alpha_b[c];
#pragma unroll
    for (int t = 0; t < T; ++t) {
        size_t idx = ((size_t)t * BS + b) * C + c;
        q_ws[idx] = accq[t] + qb;
        float aa = acca[t] + ab + 3.0f;
        alp_ws[idx] = fminf(fmaxf(aa, 0.0f), 6.0f) * (2.0f / 6.0f);
    }
}

// ---------------------------------------------------------------------------
// Kernel 2: fused attention + mlp via MFMA, split over HW.
// grid = BS*NH*S = 1792; 384 threads = 6 waves.
//   scores: S[t,n] = Q x F     (A=Q b128 frags, B=F strided-u16 frags)
//   PV+MLP: D[c,t~] = F x [P;W] (A=F b128, B=PW b128; t~0-5=O, 6-11=MLP)
// 1-deep software pipeline: chunk cc+1's global loads are issued right after
// chunk cc's LDS commit and stay in flight across the lgkm-only barriers
// while scores/softmax/PV run. NO __launch_bounds__ wave clamp: R2 showed
// clamping to 6 waves/EU forces VGPR=40 -> prefetch spills to scratch
// (WRITE_SIZE 24->168 MB). Let the allocator take what it needs.
// ---------------------------------------------------------------------------
struct PF { float4 f0, f1, f2, f3, f4, m; };

__global__ __launch_bounds__(384) void fused_attn_mlp(
    const float* __restrict__ feat,     // [BS,C,HW]
    const float* __restrict__ mlp_w,    // [T,HW]
    const float* __restrict__ q_ws,     // [T,BS,C]
    float* __restrict__ out_attn,       // [BS,NH,T,HW] (pre-softmax scores)
    float* __restrict__ o_part,         // [BS*NH*S][T][DH]
    float* __restrict__ mlp_part,       // [BS*NH*S][T][DH]
    float* __restrict__ ml_part)        // [BS*NH*S][T][2]
{
    int bh = blockIdx.x / S, sp = blockIdx.x % S;
    int b = bh / NH, h = bh % NH;
    int tid = threadIdx.x;
    int wave = tid >> 6, lane = tid & 63;
    int col = lane & 15, quad = lane >> 4;

    __shared__ unsigned short fch[DH][PNF];   // 17.4 KB bf16 features chunk
    __shared__ unsigned short pw[16][PNF];    // 4.4 KB  rows 0-5 = P, 6-11 = W, 12-15 = 0
    __shared__ unsigned short qs[16][QP];     // 2.3 KB  bf16 Q (rows 6-15 garbage; discarded)
    __shared__ float st[T][PNS];              // 2.8 KB  fp32 scores chunk
    __shared__ float m_s[T], l_s[T], al_s[T];

    const float* fbase = feat + ((size_t)b * C + h * DH) * HW;
    float* obase = out_attn + ((size_t)bh * T) * HW;

    // per-thread staging offsets (rows of 28 float4 = 112 cols)
    const int o0 = (tid / 28) * HW + 4 * (tid % 28);           // also mlp_w offset
    const int o1 = ((tid + 384) / 28) * HW + 4 * ((tid + 384) % 28);
    const int o2 = ((tid + 768) / 28) * HW + 4 * ((tid + 768) % 28);
    const int o3 = ((tid + 1152) / 28) * HW + 4 * ((tid + 1152) % 28);
    const int o4 = ((tid + 1536) / 28) * HW + 4 * ((tid + 1536) % 28);

    auto pf_issue = [&](PF& p, int n0) {
        p.f0 = *(const float4*)&fbase[o0 + n0];
        p.f1 = *(const float4*)&fbase[o1 + n0];
        p.f2 = *(const float4*)&fbase[o2 + n0];
        p.f3 = *(const float4*)&fbase[o3 + n0];
        if (tid < 256) p.f4 = *(const float4*)&fbase[o4 + n0];
        if (tid < 168) p.m  = *(const float4*)&mlp_w[o0 + n0];
    };
    auto pf_commit = [&](const PF& p) {
        st_bf8(&fch[tid / 28][4 * (tid % 28)], p.f0);
        st_bf8(&fch[(tid + 384) / 28][4 * ((tid + 384) % 28)], p.f1);
        st_bf8(&fch[(tid + 768) / 28][4 * ((tid + 768) % 28)], p.f2);
        st_bf8(&fch[(tid + 1152) / 28][4 * ((tid + 1152) % 28)], p.f3);
        if (tid < 256) st_bf8(&fch[(tid + 1536) / 28][4 * ((tid + 1536) % 28)], p.f4);
        if (tid < 168) st_bf8(&pw[6 + tid / 28][4 * (tid % 28)], p.m);
    };

    // ---- issue chunk-0 prefetch before any LDS work
    const int nsp = sp * CPB * NT;
    PF A;
    pf_issue(A, nsp);

    // ---- one-time zero of pads (staging never touches these)
    for (int i = tid; i < 16 * PNF; i += 384) pw[i / PNF][i % PNF] = 0;
    for (int i = tid; i < DH * 16; i += 384) fch[i / 16][112 + (i % 16)] = 0;
    if (tid < T) { m_s[tid] = -3e38f; l_s[tid] = 0.f; }
    // ---- stage Q bf16 (rows 0-5); one load per thread (t=wave, c2=lane)
    qs[wave][lane] = f2bf(q_ws[((size_t)wave * BS + b) * C + h * DH + lane]);

    f32x4 accPW = {0.f, 0.f, 0.f, 0.f};    // waves 0-3: [c-tile=wave][t~=col]
    wg_barrier_lgkm();

#pragma unroll 1
    for (int cc = 0; cc < CPB; ++cc) {
        const int n0 = nsp + cc * NT;

        // ---- commit prefetched chunk cc to LDS as bf16 (vmcnt wait by dep)
        pf_commit(A);
        // ---- issue chunk cc+1; stays in flight across the barriers below
        if (cc + 1 < CPB) pf_issue(A, n0 + NT);
        wg_barrier_lgkm();

        // ---- scores MFMA: n-tile(s) per wave
        for (int tile = wave; tile < 7; tile += 6) {
            bf16x8 a0 = *(const bf16x8*)&qs[col][quad * 8];
            bf16x8 a1 = *(const bf16x8*)&qs[col][32 + quad * 8];
            bf16x8 b0, b1;
#pragma unroll
            for (int j = 0; j < 8; ++j) {
                b0[j] = (short)fch[quad * 8 + j][tile * 16 + col];
                b1[j] = (short)fch[32 + quad * 8 + j][tile * 16 + col];
            }
            f32x4 acc = {0.f, 0.f, 0.f, 0.f};
            acc = __builtin_amdgcn_mfma_f32_16x16x32_bf16(a0, b0, acc, 0, 0, 0);
            acc = __builtin_amdgcn_mfma_f32_16x16x32_bf16(a1, b1, acc, 0, 0, 0);
#pragma unroll
            for (int reg = 0; reg < 4; ++reg) {
                int r = quad * 4 + reg;
                if (r < 6) st[r][tile * 16 + col] = acc[reg] * SCALE;
            }
        }
        wg_barrier_lgkm();

        // ---- online softmax (wave t) + coalesced score write-out
        {
            int t = wave;
            float v0 = st[t][lane];
            float v1 = (lane + 64 < NT) ? st[t][lane + 64] : -3e38f;
            float mloc = fmaxf(v0, v1);
#pragma unroll
            for (int off = 32; off; off >>= 1) mloc = fmaxf(mloc, __shfl_down(mloc, off));
            mloc = __shfl(mloc, 0);
            float m_old = m_s[t], m_new = fmaxf(m_old, mloc);
            float p0 = __expf(v0 - m_new);
            float p1 = (lane + 64 < NT) ? __expf(v1 - m_new) : 0.f;
            pw[t][lane] = f2bf(p0);
            if (lane + 64 < NT) pw[t][lane + 64] = f2bf(p1);
            float ssum = p0 + p1;
#pragma unroll
            for (int off = 32; off; off >>= 1) ssum += __shfl_down(ssum, off);
            if (lane == 0) {
                float alpha = __expf(m_old - m_new);
                l_s[t] = l_s[t] * alpha + ssum;
                m_s[t] = m_new;
                al_s[t] = alpha;
            }
            if (lane < NT / 4) {   // coalesced float4 out_attn write
                *(float4*)&obase[(size_t)t * HW + n0 + 4 * lane] =
                    *(const float4*)&st[t][4 * lane];
            }
        }
        wg_barrier_lgkm();

        // ---- PV + MLP MFMA: wave = c-tile (waves 0-3)
        if (wave < 4) {
            float alpha = (col < 6) ? al_s[col] : 1.0f;
            accPW *= alpha;
#pragma unroll
            for (int ks = 0; ks < 4; ++ks) {
                bf16x8 af = *(const bf16x8*)&fch[wave * 16 + col][ks * 32 + quad * 8];
                bf16x8 bf = *(const bf16x8*)&pw[col][ks * 32 + quad * 8];
                accPW = __builtin_amdgcn_mfma_f32_16x16x32_bf16(af, bf, accPW, 0, 0, 0);
            }
        }
        wg_barrier_lgkm();   // fch/pw/st reused next chunk
    }

    // ---- epilogue: scatter D tiles to partials
    if (wave < 4) {
#pragma unroll
        for (int reg = 0; reg < 4; ++reg) {
            int c2 = wave * 16 + quad * 4 + reg;   // row = channel
            if (col < 6) {
                o_part[((size_t)blockIdx.x * T + col) * DH + c2] = accPW[reg];
            } else if (col < 12) {
                mlp_part[((size_t)blockIdx.x * T + (col - 6)) * DH + c2] = accPW[reg];
            }
        }
    }
    if (tid < 2 * T) {
        int t = tid >> 1;
        ml_part[((size_t)blockIdx.x * T + t) * 2 + (tid & 1)] =
            (tid & 1) ? l_s[t] : m_s[t];
    }
}

// ---------------------------------------------------------------------------
// Kernel 3: merge split partials + gate + proj + residual + LayerNorm.
// ---------------------------------------------------------------------------
__global__ __launch_bounds__(256) void merge_proj_ln_kernel(
    const float* __restrict__ o_part,
    const float* __restrict__ mlp_part,
    const float* __restrict__ ml_part,
    const float* __restrict__ mlp_b,    // [T]
    const float* __restrict__ alp_ws,   // [T,BS,C]
    const float* __restrict__ tokens,   // [T,BS,D]
    const float* __restrict__ proj_w,   // [D,C]
    const float* __restrict__ proj_b,   // [D]
    const float* __restrict__ ln_g,     // [D]
    const float* __restrict__ ln_b,     // [D]
    float* __restrict__ out_tok)        // [T,BS,D]
{
    int tb = blockIdx.x;
    int t = tb / BS, b = tb % BS;
    int tid = threadIdx.x;
    __shared__ float g_s[C];
    __shared__ float r1[4], r2[4];

    {
        int c = tid;
        int h = c >> 6, cl = c & 63;
        int bh = b * NH + h;
        float m[S], l[S];
        float M = -3e38f;
#pragma unroll
        for (int s = 0; s < S; ++s) {
            size_t blk = (size_t)(bh * S + s);
            m[s] = ml_part[(blk * T + t) * 2 + 0];
            l[s] = ml_part[(blk * T + t) * 2 + 1];
            M = fmaxf(M, m[s]);
        }
        float L = 0.f, O = 0.f, MLP = 0.f;
#pragma unroll
        for (int s = 0; s < S; ++s) {
            float w = __expf(m[s] - M);
            size_t blk = (size_t)(bh * S + s);
            size_t pidx = (blk * T + t) * DH + cl;
            L += l[s] * w;
            O += o_part[pidx] * w;
            MLP += mlp_part[pidx];
        }
        size_t idx = (size_t)tb * C + c;
        g_s[c] = (MLP + mlp_b[t] + O / L) * alp_ws[idx];
    }
    __syncthreads();

    if (tid < D) {
        int d = tid;
        float acc = proj_b[d] + tokens[(size_t)tb * D + d];
        const float4* pr = (const float4*)(proj_w + (size_t)d * C);
#pragma unroll 8
        for (int v = 0; v < C / 4; ++v) {
            float4 w4 = pr[v];
            float4 g4 = *(const float4*)&g_s[4 * v];
            acc += w4.x * g4.x + w4.y * g4.y + w4.z * g4.z + w4.w * g4.w;
        }

        float s1 = acc, s2 = acc * acc;
#pragma unroll
        for (int off = 32; off; off >>= 1) { s1 += __shfl_down(s1, off); s2 += __shfl_down(s2, off); }
        int wv = d >> 6, lane = d & 63;
        if (lane == 0) { r1[wv] = s1; r2[wv] = s2; }
        __syncthreads();
        float sum1 = r1[0] + r1[1] + r1[2];
        float sum2 = r2[0] + r2[1] + r2[2];
        float mu = sum1 * (1.0f / D);
        float var = sum2 * (1.0f / D) - mu * mu;
        float inv = rsqrtf(var + LN_EPS);
        out_tok[(size_t)tb * D + d] = (acc - mu) * inv * ln_g[d] + ln_b[d];
    } else {
        __syncthreads();
    }
}

// ---------------------------------------------------------------------------
extern "C" void kernel_launch(void* const* d_in, const int* in_sizes, int n_in,
                              void* d_out, int out_size, void* d_ws, size_t ws_size,
                              hipStream_t stream) {
    const float* features = (const float*)d_in[0];
    const float* tokens   = (const float*)d_in[1];
    const float* mlp_w    = (const float*)d_in[2];
    const float* mlp_b    = (const float*)d_in[3];
    const float* q_w      = (const float*)d_in[4];
    const float* q_b      = (const float*)d_in[5];
    const float* alpha_w  = (const float*)d_in[6];
    const float* alpha_b  = (const float*)d_in[7];
    const float* proj_w   = (const float*)d_in[8];
    const float* proj_b   = (const float*)d_in[9];
    const float* ln_g     = (const float*)d_in[10];
    const float* ln_b     = (const float*)d_in[11];

    float* out_tok  = (float*)d_out;                   // [T,BS,D]
    float* out_attn = (float*)d_out + T * BS * D;      // [BS,NH,T,HW]

    constexpr int NBLK = BS * NH * S;                  // 1792
    float* q_ws     = (float*)d_ws;                    // T*BS*C
    float* alp_ws   = q_ws + T * BS * C;               // T*BS*C
    float* ml_part  = alp_ws + T * BS * C;             // NBLK*T*2
    float* o_part   = ml_part + NBLK * T * 2;          // NBLK*T*DH
    float* mlp_part = o_part + NBLK * T * DH;          // NBLK*T*DH

    qalpha_kernel<<<BS, 256, 0, stream>>>(
        tokens, q_w, q_b, alpha_w, alpha_b, q_ws, alp_ws);

    fused_attn_mlp<<<NBLK, 384, 0, stream>>>(
        features, mlp_w, q_ws, out_attn, o_part, mlp_part, ml_part);

    merge_proj_ln_kernel<<<T * BS, 256, 0, stream>>>(
        o_part, mlp_part, ml_part, mlp_b, alp_ws, tokens,
        proj_w, proj_b, ln_g, ln_b, out_tok);
}